// Round 16
// baseline (134.956 us; speedup 1.0000x reference)
//
#include <hip/hip_runtime.h>
#include <hip/hip_bf16.h>
#include <cmath>

#define NTOK 4096

typedef float        f32x16 __attribute__((ext_vector_type(16)));
typedef short        s16x8  __attribute__((ext_vector_type(8)));
typedef unsigned int u32x4  __attribute__((ext_vector_type(4)));

__device__ __forceinline__ unsigned short f2bf(float f) {
    __hip_bfloat16 h = __float2bfloat16(f);
    return *reinterpret_cast<unsigned short*>(&h);
}
__device__ __forceinline__ float bf2f(unsigned short u) {
    __hip_bfloat16 h = *reinterpret_cast<__hip_bfloat16*>(&u);
    return __bfloat162float(h);
}
// packed f32x2 -> bf16x2 via HIP intrinsic (lowers to v_cvt_pk_bf16_f32)
__device__ __forceinline__ unsigned pk2(float a, float b) {
    __hip_bfloat162 h = __float22bfloat162_rn(make_float2(a, b));
    return *reinterpret_cast<unsigned*>(&h);
}

// ---------------------------------------------------------------------------
// Kernel 1: QKV projection, 10-part x c-split-4 (unchanged R15).
// ---------------------------------------------------------------------------
__global__ __launch_bounds__(256)
void qkv_kernel(const float* __restrict__ x,
                const float* __restrict__ Wq, const float* __restrict__ bq,
                const float* __restrict__ Wk, const float* __restrict__ bk,
                const float* __restrict__ Wv, const float* __restrict__ bv,
                unsigned short* __restrict__ qt2, unsigned short* __restrict__ kt2,
                unsigned short* __restrict__ vt)
{
    __shared__ float wlds[8 * 64];       // this part's 8 weight rows
    __shared__ float blds[8];
    __shared__ float pacc[4][64][9];     // per-wave partials, padded

    const int t    = threadIdx.x;        // 0..255
    const int lane = t & 63;             // voxel within group
    const int wv   = t >> 6;             // 0..3 (c-quarter)
    const int part = blockIdx.x >> 8;    // 0..9
    const int vg   = blockIdx.x & 255;

    if (t < 128) {
        const int row  = t >> 4;             // 0..7
        const int col4 = t & 15;
        const int g    = part * 8 + row;
        const float* src = (g < 8)  ? (Wq + g * 64)
                         : (g < 16) ? (Wk + (g - 8) * 64)
                                    : (Wv + (g - 16) * 64);
        ((float4*)wlds)[t] = ((const float4*)src)[col4];
        if (t < 8) {
            const int gg = part * 8 + t;
            blds[t] = (gg < 8) ? bq[gg] : (gg < 16) ? bk[gg - 8] : bv[gg - 16];
        }
    }
    __syncthreads();

    const int gid = vg * 64 + lane;
    const int b = gid >> 12;
    const int i = gid & (NTOK - 1);

    const float* xb = x + ((size_t)b * 64 + 16 * wv) * NTOK + i;
    float xv[16];
    #pragma unroll
    for (int c = 0; c < 16; c++) xv[c] = xb[(size_t)c * NTOK];

    float a[8];
    #pragma unroll
    for (int o = 0; o < 8; o++) a[o] = 0.f;
    #pragma unroll
    for (int c4 = 0; c4 < 4; c4++) {
        #pragma unroll
        for (int o = 0; o < 8; o++) {
            const float4 wv4 = ((const float4*)wlds)[o * 16 + wv * 4 + c4];
            a[o] += wv4.x * xv[c4*4+0] + wv4.y * xv[c4*4+1]
                  + wv4.z * xv[c4*4+2] + wv4.w * xv[c4*4+3];
        }
    }
    #pragma unroll
    for (int o = 0; o < 8; o++) pacc[wv][lane][o] = a[o];
    __syncthreads();

    const int ob = 2 * wv;
    float fin[2];
    #pragma unroll
    for (int oo = 0; oo < 2; oo++)
        fin[oo] = ((pacc[0][lane][ob + oo] + pacc[1][lane][ob + oo])
                +  (pacc[2][lane][ob + oo] + pacc[3][lane][ob + oo]))
                + blds[ob + oo];

    const size_t row = (size_t)b * NTOK + i;
    if (part < 2) {
        if (part == 0) {
            const float LOG2E = 1.4426950408889634f;
            fin[0] *= LOG2E; fin[1] *= LOG2E;
        }
        unsigned short hu[2], lu[2];
        #pragma unroll
        for (int oo = 0; oo < 2; oo++) {
            hu[oo] = f2bf(fin[oo]);
            lu[oo] = f2bf(fin[oo] - bf2f(hu[oo]));
        }
        unsigned short* dst = (part == 0 ? qt2 : kt2) + row * 16 + ob;
        *(unsigned*)dst       = *(const unsigned*)hu;
        *(unsigned*)(dst + 8) = *(const unsigned*)lu;
    } else {
        const int jl   = i & 15;
        const int slot = (jl & 3) | ((jl & 4) << 1) | ((jl & 8) >> 1);  // swap b2<->b3
        const int cbase = (part - 2) * 8 + ob;
        unsigned short* vdst =
            vt + ((size_t)b * 256 + (i >> 4)) * 1024 + (size_t)cbase * 16 + slot;
        vdst[0]  = f2bf(fin[0]);
        vdst[16] = f2bf(fin[1]);
    }
}

// ---------------------------------------------------------------------------
// Kernel 2: fused flash attention (R15 structure) with IN-KERNEL rep=3.
// MEASUREMENT: reps make this dispatch ~45-57 us so it finally beats the
// ~40 us harness fills into rocprof's top-5 -> first attn counters since R3.
// Idempotent: acc/lsum re-zeroed per rep, same output written each rep.
// attn_true = dispatch_dur / 3.
// ---------------------------------------------------------------------------
__global__ __launch_bounds__(512)
void attn_kernel(const unsigned short* __restrict__ qt2,
                 const unsigned short* __restrict__ kt2,
                 const unsigned short* __restrict__ vt,
                 const float* __restrict__ x,
                 const float* __restrict__ gamma,
                 float* __restrict__ out)
{
    __shared__ float slds[4][64][64];   // merge slots [c][q], 64 KB
    __shared__ float sldl[4][64];       // l per slot

    const int t    = threadIdx.x;
    const int l    = t & 63;
    const int wv   = t >> 6;
    const int lo31 = l & 31;
    const int h    = l >> 5;
    const int w     = blockIdx.x;
    const int b     = w >> 6;
    const int qbase = (w & 63) << 6;    // 64 q per block
    const int j0    = wv << 9;          // 512 j per wave

    // Q B-frags for both q-tiles: B1 = [q_hi|q_hi], B2 = [q_lo|0]
    const unsigned short* qrow0 = qt2 + ((size_t)b * NTOK + qbase + lo31) * 16;
    const unsigned short* qrow1 = qrow0 + 32 * 16;
    s16x8 qB1_0 = *(const s16x8*)qrow0;
    s16x8 qB1_1 = *(const s16x8*)qrow1;
    s16x8 qB2_0, qB2_1;
    if (h == 0) { qB2_0 = *(const s16x8*)(qrow0 + 8); qB2_1 = *(const s16x8*)(qrow1 + 8); }
    else { u32x4 z = {0,0,0,0}; qB2_0 = __builtin_bit_cast(s16x8, z); qB2_1 = qB2_0; }

    const unsigned short* kb  = kt2 + (size_t)b * NTOK * 16 + (size_t)h * 8;
    const unsigned short* vbA = vt + (size_t)b * NTOK * 64 + (size_t)lo31 * 16 + 8 * h;
    const unsigned short* vbB = vbA + 512;

    s16x8 K[3], V00[3], V01[3], V10[3], V11[3];

    #define LOADSET(s_, a_) do {                                              \
        K[s_]   = *(const s16x8*)(kb + (size_t)(j0 + ((a_) << 5) + lo31) * 16);  \
        V00[s_] = *(const s16x8*)(vbA + (size_t)((j0 >> 4) + ((a_) << 1)) * 1024);     \
        V01[s_] = *(const s16x8*)(vbA + (size_t)((j0 >> 4) + ((a_) << 1) + 1) * 1024); \
        V10[s_] = *(const s16x8*)(vbB + (size_t)((j0 >> 4) + ((a_) << 1)) * 1024);     \
        V11[s_] = *(const s16x8*)(vbB + (size_t)((j0 >> 4) + ((a_) << 1) + 1) * 1024); \
    } while (0)

    #pragma unroll 1
    for (int rep = 0; rep < 3; ++rep) {

        f32x16 accA0, accB0, accA1, accB1, zf;
        #pragma unroll
        for (int r = 0; r < 16; r++) {
            accA0[r]=0.f; accB0[r]=0.f; accA1[r]=0.f; accB1[r]=0.f; zf[r]=0.f;
        }
        float lsum0 = 0.f, lsum1 = 0.f;

        LOADSET(0, 0);
        LOADSET(1, 1);

        #pragma unroll
        for (int it = 0; it < 16; ++it) {
            const int nx = it + 2;
            LOADSET((it + 2) % 3, (nx < 16) ? nx : 0);
            const int cu = it % 3;

            f32x16 s0, s1;
            s0 = __builtin_amdgcn_mfma_f32_32x32x16_bf16(K[cu], qB1_0, zf, 0, 0, 0);
            s0 = __builtin_amdgcn_mfma_f32_32x32x16_bf16(K[cu], qB2_0, s0, 0, 0, 0);
            s1 = __builtin_amdgcn_mfma_f32_32x32x16_bf16(K[cu], qB1_1, zf, 0, 0, 0);
            s1 = __builtin_amdgcn_mfma_f32_32x32x16_bf16(K[cu], qB2_1, s1, 0, 0, 0);

            #pragma unroll
            for (int r = 0; r < 16; r++) s0[r] = __builtin_amdgcn_exp2f(s0[r]);
            #pragma unroll
            for (int r = 0; r < 16; r++) s1[r] = __builtin_amdgcn_exp2f(s1[r]);

            lsum0 += ((s0[0]+s0[1])+(s0[2]+s0[3])) + ((s0[4]+s0[5])+(s0[6]+s0[7]))
                   + ((s0[8]+s0[9])+(s0[10]+s0[11])) + ((s0[12]+s0[13])+(s0[14]+s0[15]));
            lsum1 += ((s1[0]+s1[1])+(s1[2]+s1[3])) + ((s1[4]+s1[5])+(s1[6]+s1[7]))
                   + ((s1[8]+s1[9])+(s1[10]+s1[11])) + ((s1[12]+s1[13])+(s1[14]+s1[15]));

            u32x4 wa0, wc0, wa1, wc1;
            wa0.x = pk2(s0[0], s0[1]);   wa0.y = pk2(s0[2], s0[3]);
            wa0.z = pk2(s0[4], s0[5]);   wa0.w = pk2(s0[6], s0[7]);
            wc0.x = pk2(s0[8], s0[9]);   wc0.y = pk2(s0[10], s0[11]);
            wc0.z = pk2(s0[12], s0[13]); wc0.w = pk2(s0[14], s0[15]);
            wa1.x = pk2(s1[0], s1[1]);   wa1.y = pk2(s1[2], s1[3]);
            wa1.z = pk2(s1[4], s1[5]);   wa1.w = pk2(s1[6], s1[7]);
            wc1.x = pk2(s1[8], s1[9]);   wc1.y = pk2(s1[10], s1[11]);
            wc1.z = pk2(s1[12], s1[13]); wc1.w = pk2(s1[14], s1[15]);
            s16x8 pf0_0 = __builtin_bit_cast(s16x8, wa0);
            s16x8 pf1_0 = __builtin_bit_cast(s16x8, wc0);
            s16x8 pf0_1 = __builtin_bit_cast(s16x8, wa1);
            s16x8 pf1_1 = __builtin_bit_cast(s16x8, wc1);

            __builtin_amdgcn_s_setprio(1);
            accA0 = __builtin_amdgcn_mfma_f32_32x32x16_bf16(V00[cu], pf0_0, accA0, 0, 0, 0);
            accA0 = __builtin_amdgcn_mfma_f32_32x32x16_bf16(V01[cu], pf1_0, accA0, 0, 0, 0);
            accB0 = __builtin_amdgcn_mfma_f32_32x32x16_bf16(V10[cu], pf0_0, accB0, 0, 0, 0);
            accB0 = __builtin_amdgcn_mfma_f32_32x32x16_bf16(V11[cu], pf1_0, accB0, 0, 0, 0);
            accA1 = __builtin_amdgcn_mfma_f32_32x32x16_bf16(V00[cu], pf0_1, accA1, 0, 0, 0);
            accA1 = __builtin_amdgcn_mfma_f32_32x32x16_bf16(V01[cu], pf1_1, accA1, 0, 0, 0);
            accB1 = __builtin_amdgcn_mfma_f32_32x32x16_bf16(V10[cu], pf0_1, accB1, 0, 0, 0);
            accB1 = __builtin_amdgcn_mfma_f32_32x32x16_bf16(V11[cu], pf1_1, accB1, 0, 0, 0);
            __builtin_amdgcn_s_setprio(0);
        }

        lsum0 += __shfl_xor(lsum0, 32);
        lsum1 += __shfl_xor(lsum1, 32);

        #define WR_SLOT(sidx) do {                                            \
            const int s_ = (sidx);                                            \
            _Pragma("unroll")                                                 \
            for (int r = 0; r < 16; r++) {                                    \
                const int c_ = (r & 3) + 8 * (r >> 2) + 4 * h;                \
                slds[s_][c_][lo31]           = accA0[r];                      \
                slds[s_][c_ + 32][lo31]      = accB0[r];                      \
                slds[s_][c_][lo31 + 32]      = accA1[r];                      \
                slds[s_][c_ + 32][lo31 + 32] = accB1[r];                      \
            }                                                                 \
            if (h == 0) { sldl[s_][lo31] = lsum0; sldl[s_][lo31 + 32] = lsum1; } \
        } while (0)

        #define MRG_SLOT(sidx) do {                                           \
            const int s_ = (sidx);                                            \
            _Pragma("unroll")                                                 \
            for (int r = 0; r < 16; r++) {                                    \
                const int c_ = (r & 3) + 8 * (r >> 2) + 4 * h;                \
                accA0[r] += slds[s_][c_][lo31];                               \
                accB0[r] += slds[s_][c_ + 32][lo31];                          \
                accA1[r] += slds[s_][c_][lo31 + 32];                          \
                accB1[r] += slds[s_][c_ + 32][lo31 + 32];                     \
            }                                                                 \
            lsum0 += sldl[s_][lo31];                                          \
            lsum1 += sldl[s_][lo31 + 32];                                     \
        } while (0)

        if (wv >= 4) WR_SLOT(wv - 4);
        __syncthreads();
        if (wv < 4) MRG_SLOT(wv);
        __syncthreads();
        if (wv == 2 || wv == 3) WR_SLOT(wv - 2);
        __syncthreads();
        if (wv < 2) MRG_SLOT(wv);
        __syncthreads();
        if (wv == 1) WR_SLOT(0);
        __syncthreads();
        if (wv == 0) { MRG_SLOT(0); WR_SLOT(0); }
        __syncthreads();

        // ---- fused epilogue: out = gamma*acc/L + x ----
        const int c  = t >> 3;              // 0..63
        const int q8 = (t & 7) << 3;        // 0,8,..,56
        const float g = gamma[0];
        const size_t off = (((size_t)b * 64 + c) << 12) + qbase + q8;
        #pragma unroll
        for (int half = 0; half < 2; half++) {
            const float4 a4 = *(const float4*)&slds[0][c][q8 + half * 4];
            const float4 xv4 = *(const float4*)(x + off + half * 4);
            float4 o;
            o.x = a4.x * (g / sldl[0][q8 + half*4 + 0]) + xv4.x;
            o.y = a4.y * (g / sldl[0][q8 + half*4 + 1]) + xv4.y;
            o.z = a4.z * (g / sldl[0][q8 + half*4 + 2]) + xv4.z;
            o.w = a4.w * (g / sldl[0][q8 + half*4 + 3]) + xv4.w;
            *(float4*)(out + off + half * 4) = o;
        }
        __syncthreads();   // protect slds reuse across reps
    }
}

// ---------------------------------------------------------------------------
extern "C" void kernel_launch(void* const* d_in, const int* in_sizes, int n_in,
                              void* d_out, int out_size, void* d_ws, size_t ws_size,
                              hipStream_t stream) {
    const float* x     = (const float*)d_in[0];
    const float* Wq    = (const float*)d_in[1];
    const float* bq    = (const float*)d_in[2];
    const float* Wk    = (const float*)d_in[3];
    const float* bk    = (const float*)d_in[4];
    const float* Wv    = (const float*)d_in[5];
    const float* bv    = (const float*)d_in[6];
    const float* gamma = (const float*)d_in[7];
    float* out = (float*)d_out;

    unsigned short* qt2 = (unsigned short*)d_ws;            // 4*4096*16 bf16
    unsigned short* kt2 = qt2 + (size_t)4 * NTOK * 16;      // 4*4096*16 bf16
    unsigned short* vt  = kt2 + (size_t)4 * NTOK * 16;      // 4*4096*64 bf16 (tiled+permuted)

    qkv_kernel<<<2560, 256, 0, stream>>>(x, Wq, bq, Wk, bk, Wv, bv, qt2, kt2, vt);
    attn_kernel<<<256, 512, 0, stream>>>(qt2, kt2, vt, x, gamma, out);
}

// Round 17
// 31.915 us; speedup vs baseline: 4.2286x; 4.2286x over previous
//
#include <hip/hip_runtime.h>
#include <hip/hip_bf16.h>
#include <cmath>

#define NTOK 4096

typedef float        f32x16 __attribute__((ext_vector_type(16)));
typedef short        s16x8  __attribute__((ext_vector_type(8)));
typedef unsigned int u32x4  __attribute__((ext_vector_type(4)));

__device__ __forceinline__ unsigned short f2bf(float f) {
    __hip_bfloat16 h = __float2bfloat16(f);
    return *reinterpret_cast<unsigned short*>(&h);
}
__device__ __forceinline__ float bf2f(unsigned short u) {
    __hip_bfloat16 h = *reinterpret_cast<__hip_bfloat16*>(&u);
    return __bfloat162float(h);
}
// packed f32x2 -> bf16x2 via HIP intrinsic (lowers to v_cvt_pk_bf16_f32)
__device__ __forceinline__ unsigned pk2(float a, float b) {
    __hip_bfloat162 h = __float22bfloat162_rn(make_float2(a, b));
    return *reinterpret_cast<unsigned*>(&h);
}

// ---------------------------------------------------------------------------
// Kernel 1: QKV projection, 10-part x c-split-4 (unchanged R15).
// ---------------------------------------------------------------------------
__global__ __launch_bounds__(256)
void qkv_kernel(const float* __restrict__ x,
                const float* __restrict__ Wq, const float* __restrict__ bq,
                const float* __restrict__ Wk, const float* __restrict__ bk,
                const float* __restrict__ Wv, const float* __restrict__ bv,
                unsigned short* __restrict__ qt2, unsigned short* __restrict__ kt2,
                unsigned short* __restrict__ vt)
{
    __shared__ float wlds[8 * 64];       // this part's 8 weight rows
    __shared__ float blds[8];
    __shared__ float pacc[4][64][9];     // per-wave partials, padded

    const int t    = threadIdx.x;        // 0..255
    const int lane = t & 63;             // voxel within group
    const int wv   = t >> 6;             // 0..3 (c-quarter)
    const int part = blockIdx.x >> 8;    // 0..9
    const int vg   = blockIdx.x & 255;

    if (t < 128) {
        const int row  = t >> 4;             // 0..7
        const int col4 = t & 15;
        const int g    = part * 8 + row;
        const float* src = (g < 8)  ? (Wq + g * 64)
                         : (g < 16) ? (Wk + (g - 8) * 64)
                                    : (Wv + (g - 16) * 64);
        ((float4*)wlds)[t] = ((const float4*)src)[col4];
        if (t < 8) {
            const int gg = part * 8 + t;
            blds[t] = (gg < 8) ? bq[gg] : (gg < 16) ? bk[gg - 8] : bv[gg - 16];
        }
    }
    __syncthreads();

    const int gid = vg * 64 + lane;
    const int b = gid >> 12;
    const int i = gid & (NTOK - 1);

    const float* xb = x + ((size_t)b * 64 + 16 * wv) * NTOK + i;
    float xv[16];
    #pragma unroll
    for (int c = 0; c < 16; c++) xv[c] = xb[(size_t)c * NTOK];

    float a[8];
    #pragma unroll
    for (int o = 0; o < 8; o++) a[o] = 0.f;
    #pragma unroll
    for (int c4 = 0; c4 < 4; c4++) {
        #pragma unroll
        for (int o = 0; o < 8; o++) {
            const float4 wv4 = ((const float4*)wlds)[o * 16 + wv * 4 + c4];
            a[o] += wv4.x * xv[c4*4+0] + wv4.y * xv[c4*4+1]
                  + wv4.z * xv[c4*4+2] + wv4.w * xv[c4*4+3];
        }
    }
    #pragma unroll
    for (int o = 0; o < 8; o++) pacc[wv][lane][o] = a[o];
    __syncthreads();

    const int ob = 2 * wv;
    float fin[2];
    #pragma unroll
    for (int oo = 0; oo < 2; oo++)
        fin[oo] = ((pacc[0][lane][ob + oo] + pacc[1][lane][ob + oo])
                +  (pacc[2][lane][ob + oo] + pacc[3][lane][ob + oo]))
                + blds[ob + oo];

    const size_t row = (size_t)b * NTOK + i;
    if (part < 2) {
        if (part == 0) {
            const float LOG2E = 1.4426950408889634f;
            fin[0] *= LOG2E; fin[1] *= LOG2E;
        }
        unsigned short hu[2], lu[2];
        #pragma unroll
        for (int oo = 0; oo < 2; oo++) {
            hu[oo] = f2bf(fin[oo]);
            lu[oo] = f2bf(fin[oo] - bf2f(hu[oo]));
        }
        unsigned short* dst = (part == 0 ? qt2 : kt2) + row * 16 + ob;
        *(unsigned*)dst       = *(const unsigned*)hu;
        *(unsigned*)(dst + 8) = *(const unsigned*)lu;
    } else {
        const int jl   = i & 15;
        const int slot = (jl & 3) | ((jl & 4) << 1) | ((jl & 8) >> 1);  // swap b2<->b3
        const int cbase = (part - 2) * 8 + ob;
        unsigned short* vdst =
            vt + ((size_t)b * 256 + (i >> 4)) * 1024 + (size_t)cbase * 16 + slot;
        vdst[0]  = f2bf(fin[0]);
        vdst[16] = f2bf(fin[1]);
    }
}

// ---------------------------------------------------------------------------
// Kernel 2: fused flash attention with WAVE-PAIRING.  R16 counters showed
// the 64q-per-wave design spills (VGPR cap 128 vs ~190 needed; 176 MB
// scratch writes).  Here: 16 waves/block (1024 thr) on a 64-q tile; waves
// (2k, 2k+1) share j-range [k*512,k*512+512) but handle different q-tiles
// -> the pair issues IDENTICAL K/V addresses and the trailing wave hits L1
// (per-CU) -> L2-side K/V traffic halves, while per-wave registers stay at
// the lean 32q level (~120 <= the 128 cap a 1024-thr block enforces).
// Grid 256 (1 block/CU, 16 waves/CU).  No-max exp2 softmax, zero
// cross-lane j-loop, per-q-tile additive LDS merge in disjoint columns.
// ---------------------------------------------------------------------------
__global__ __launch_bounds__(1024)
void attn_kernel(const unsigned short* __restrict__ qt2,
                 const unsigned short* __restrict__ kt2,
                 const unsigned short* __restrict__ vt,
                 const float* __restrict__ x,
                 const float* __restrict__ gamma,
                 float* __restrict__ out)
{
    __shared__ float slds[4][64][64];   // merge slots [c][q 0..63], 64 KB
    __shared__ float sldl[4][64];       // l per slot

    const int t    = threadIdx.x;       // 0..1023
    const int l    = t & 63;
    const int wv   = t >> 6;            // 0..15
    const int qt   = wv & 1;            // q-tile of this wave (pairing key)
    const int u    = wv >> 1;           // 0..7 j-range id (shared by pair)
    const int lo31 = l & 31;
    const int h    = l >> 5;
    const int w     = blockIdx.x;
    const int b     = w >> 6;
    const int qbase = (w & 63) << 6;    // 64 q per block
    const int j0    = u << 9;           // 512 j per wave

    // Q B-frags: B1 = [q_hi|q_hi], B2 = [q_lo|0]
    const unsigned short* qrow =
        qt2 + ((size_t)b * NTOK + qbase + qt * 32 + lo31) * 16;
    s16x8 qB1 = *(const s16x8*)qrow;
    s16x8 qB2;
    if (h == 0) qB2 = *(const s16x8*)(qrow + 8);
    else        { u32x4 z = {0,0,0,0}; qB2 = __builtin_bit_cast(s16x8, z); }

    // K/V addresses depend only on (b, h, lo31, j0) -> identical for a pair
    const unsigned short* kb  = kt2 + (size_t)b * NTOK * 16 + (size_t)h * 8;
    const unsigned short* vbA = vt + (size_t)b * NTOK * 64 + (size_t)lo31 * 16 + 8 * h;
    const unsigned short* vbB = vbA + 512;

    f32x16 accA, accB;
    #pragma unroll
    for (int r = 0; r < 16; r++) { accA[r] = 0.f; accB[r] = 0.f; }
    float lsum = 0.f;

    s16x8 K[2], V00[2], V01[2], V10[2], V11[2];

    #define LOADSET(s_, a_) do {                                              \
        K[s_]   = *(const s16x8*)(kb + (size_t)(j0 + ((a_) << 5) + lo31) * 16);  \
        V00[s_] = *(const s16x8*)(vbA + (size_t)((j0 >> 4) + ((a_) << 1)) * 1024);     \
        V01[s_] = *(const s16x8*)(vbA + (size_t)((j0 >> 4) + ((a_) << 1) + 1) * 1024); \
        V10[s_] = *(const s16x8*)(vbB + (size_t)((j0 >> 4) + ((a_) << 1)) * 1024);     \
        V11[s_] = *(const s16x8*)(vbB + (size_t)((j0 >> 4) + ((a_) << 1) + 1) * 1024); \
    } while (0)

    LOADSET(0, 0);

    #pragma unroll
    for (int it = 0; it < 16; ++it) {
        const int cu = it & 1;
        const int nx = it + 1;
        LOADSET(cu ^ 1, (nx < 16) ? nx : 0);   // issue next-chunk loads first

        f32x16 s;
        #pragma unroll
        for (int r = 0; r < 16; r++) s[r] = 0.f;
        s = __builtin_amdgcn_mfma_f32_32x32x16_bf16(K[cu], qB1, s, 0, 0, 0);
        s = __builtin_amdgcn_mfma_f32_32x32x16_bf16(K[cu], qB2, s, 0, 0, 0);

        // ---- p = exp2(s) raw (no max needed: CQ=8 keeps |s| small) ----
        #pragma unroll
        for (int r = 0; r < 16; r++) s[r] = __builtin_amdgcn_exp2f(s[r]);

        lsum += ((s[0]+s[1])+(s[2]+s[3])) + ((s[4]+s[5])+(s[6]+s[7]))
              + ((s[8]+s[9])+(s[10]+s[11])) + ((s[12]+s[13])+(s[14]+s[15]));

        // ---- P^T -> B-frags: direct repack of own registers ----
        u32x4 wa, wc;
        wa.x = pk2(s[0], s[1]);   wa.y = pk2(s[2], s[3]);
        wa.z = pk2(s[4], s[5]);   wa.w = pk2(s[6], s[7]);
        wc.x = pk2(s[8], s[9]);   wc.y = pk2(s[10], s[11]);
        wc.z = pk2(s[12], s[13]); wc.w = pk2(s[14], s[15]);
        s16x8 pf0 = __builtin_bit_cast(s16x8, wa);
        s16x8 pf1 = __builtin_bit_cast(s16x8, wc);

        __builtin_amdgcn_s_setprio(1);
        accA = __builtin_amdgcn_mfma_f32_32x32x16_bf16(V00[cu], pf0, accA, 0, 0, 0);
        accA = __builtin_amdgcn_mfma_f32_32x32x16_bf16(V01[cu], pf1, accA, 0, 0, 0);
        accB = __builtin_amdgcn_mfma_f32_32x32x16_bf16(V10[cu], pf0, accB, 0, 0, 0);
        accB = __builtin_amdgcn_mfma_f32_32x32x16_bf16(V11[cu], pf1, accB, 0, 0, 0);
        __builtin_amdgcn_s_setprio(0);
    }

    // combine halves of l once
    lsum += __shfl_xor(lsum, 32);

    // ---- per-q-tile additive LDS tree merge (disjoint columns qt*32+..) ----
    #define WR_SLOT(sidx) do {                                                \
        const int s_ = (sidx);                                                \
        _Pragma("unroll")                                                     \
        for (int r = 0; r < 16; r++) {                                        \
            const int c_ = (r & 3) + 8 * (r >> 2) + 4 * h;                    \
            slds[s_][c_][qt * 32 + lo31]      = accA[r];                      \
            slds[s_][c_ + 32][qt * 32 + lo31] = accB[r];                      \
        }                                                                     \
        if (h == 0) sldl[s_][qt * 32 + lo31] = lsum;                          \
    } while (0)

    #define MRG_SLOT(sidx) do {                                               \
        const int s_ = (sidx);                                                \
        _Pragma("unroll")                                                     \
        for (int r = 0; r < 16; r++) {                                        \
            const int c_ = (r & 3) + 8 * (r >> 2) + 4 * h;                    \
            accA[r] += slds[s_][c_][qt * 32 + lo31];                          \
            accB[r] += slds[s_][c_ + 32][qt * 32 + lo31];                     \
        }                                                                     \
        lsum += sldl[s_][qt * 32 + lo31];                                     \
    } while (0)

    if (u >= 4) WR_SLOT(u - 4);
    __syncthreads();
    if (u < 4) MRG_SLOT(u);
    __syncthreads();
    if (u == 2 || u == 3) WR_SLOT(u - 2);
    __syncthreads();
    if (u < 2) MRG_SLOT(u);
    __syncthreads();
    if (u == 1) WR_SLOT(0);
    __syncthreads();
    if (u == 0) { MRG_SLOT(0); WR_SLOT(0); }
    __syncthreads();

    // ---- fused epilogue: out = gamma*acc/L + x, all 1024 threads ----
    const int c  = t >> 4;              // 0..63
    const int q4 = (t & 15) << 2;       // 0,4,..,60
    const float g = gamma[0];
    const float4 a4 = *(const float4*)&slds[0][c][q4];
    const float g0 = g / sldl[0][q4 + 0];
    const float g1 = g / sldl[0][q4 + 1];
    const float g2 = g / sldl[0][q4 + 2];
    const float g3 = g / sldl[0][q4 + 3];
    const size_t off = (((size_t)b * 64 + c) << 12) + qbase + q4;
    const float4 xv4 = *(const float4*)(x + off);
    float4 o;
    o.x = a4.x * g0 + xv4.x;
    o.y = a4.y * g1 + xv4.y;
    o.z = a4.z * g2 + xv4.z;
    o.w = a4.w * g3 + xv4.w;
    *(float4*)(out + off) = o;
}

// ---------------------------------------------------------------------------
extern "C" void kernel_launch(void* const* d_in, const int* in_sizes, int n_in,
                              void* d_out, int out_size, void* d_ws, size_t ws_size,
                              hipStream_t stream) {
    const float* x     = (const float*)d_in[0];
    const float* Wq    = (const float*)d_in[1];
    const float* bq    = (const float*)d_in[2];
    const float* Wk    = (const float*)d_in[3];
    const float* bk    = (const float*)d_in[4];
    const float* Wv    = (const float*)d_in[5];
    const float* bv    = (const float*)d_in[6];
    const float* gamma = (const float*)d_in[7];
    float* out = (float*)d_out;

    unsigned short* qt2 = (unsigned short*)d_ws;            // 4*4096*16 bf16
    unsigned short* kt2 = qt2 + (size_t)4 * NTOK * 16;      // 4*4096*16 bf16
    unsigned short* vt  = kt2 + (size_t)4 * NTOK * 16;      // 4*4096*64 bf16 (tiled+permuted)

    qkv_kernel<<<2560, 256, 0, stream>>>(x, Wq, bq, Wk, bk, Wv, bv, qt2, kt2, vt);
    attn_kernel<<<256, 1024, 0, stream>>>(qt2, kt2, vt, x, gamma, out);
}

// Round 18
// 31.899 us; speedup vs baseline: 4.2308x; 1.0005x over previous
//
#include <hip/hip_runtime.h>
#include <hip/hip_bf16.h>
#include <cmath>

#define NTOK 4096

typedef float        f32x16 __attribute__((ext_vector_type(16)));
typedef short        s16x8  __attribute__((ext_vector_type(8)));
typedef unsigned int u32x4  __attribute__((ext_vector_type(4)));

__device__ __forceinline__ unsigned short f2bf(float f) {
    __hip_bfloat16 h = __float2bfloat16(f);
    return *reinterpret_cast<unsigned short*>(&h);
}
__device__ __forceinline__ float bf2f(unsigned short u) {
    __hip_bfloat16 h = *reinterpret_cast<__hip_bfloat16*>(&u);
    return __bfloat162float(h);
}
// packed f32x2 -> bf16x2 via HIP intrinsic (lowers to v_cvt_pk_bf16_f32)
__device__ __forceinline__ unsigned pk2(float a, float b) {
    __hip_bfloat162 h = __float22bfloat162_rn(make_float2(a, b));
    return *reinterpret_cast<unsigned*>(&h);
}

// ---------------------------------------------------------------------------
// Kernel 1: QKV projection, 5-part x 2-chunk x c-split-4.
// R15's 10-part version: 16 x-loads per 128 FMA, x read 10x (40 MB L2).
// Now each block's xv[16] feeds TWO chunks (16 outputs): loads amortized
// 2x, x read 5x (20 MB).  Grid 1280 = part*256 + vg (XCD = vg%8 pinned),
// 256 thr, 5120 waves = 5/SIMD.  pacc reduce + store per chunk.
// Outputs unchanged: qt2/kt2 [b][i][16]=[hi|lo] (q log2e-scaled),
// vt[b][i/16][c][sigma(i%16)] j-tiled + slot-permuted.
// ---------------------------------------------------------------------------
__global__ __launch_bounds__(256)
void qkv_kernel(const float* __restrict__ x,
                const float* __restrict__ Wq, const float* __restrict__ bq,
                const float* __restrict__ Wk, const float* __restrict__ bk,
                const float* __restrict__ Wv, const float* __restrict__ bv,
                unsigned short* __restrict__ qt2, unsigned short* __restrict__ kt2,
                unsigned short* __restrict__ vt)
{
    __shared__ float wlds[16 * 64];      // this part's 16 weight rows (4 KB)
    __shared__ float blds[16];
    __shared__ float pacc[4][64][9];     // per-wave partials, padded

    const int t    = threadIdx.x;        // 0..255
    const int lane = t & 63;             // voxel within group
    const int wv   = t >> 6;             // 0..3 (c-quarter)
    const int part = blockIdx.x >> 8;    // 0..4
    const int vg   = blockIdx.x & 255;

    // stage this part's 16 weight rows + biases
    {
        const int row  = t >> 4;             // 0..15
        const int col4 = t & 15;
        const int g    = part * 16 + row;
        const float* src = (g < 8)  ? (Wq + g * 64)
                         : (g < 16) ? (Wk + (g - 8) * 64)
                                    : (Wv + (g - 16) * 64);
        ((float4*)wlds)[t] = ((const float4*)src)[col4];
        if (t < 16) {
            const int gg = part * 16 + t;
            blds[t] = (gg < 8) ? bq[gg] : (gg < 16) ? bk[gg - 8] : bv[gg - 16];
        }
    }
    __syncthreads();

    const int gid = vg * 64 + lane;
    const int b = gid >> 12;
    const int i = gid & (NTOK - 1);

    // wave wv covers channels [16*wv, 16*wv+16) -- loaded ONCE, used 2x
    const float* xb = x + ((size_t)b * 64 + 16 * wv) * NTOK + i;
    float xv[16];
    #pragma unroll
    for (int c = 0; c < 16; c++) xv[c] = xb[(size_t)c * NTOK];

    const size_t row = (size_t)b * NTOK + i;
    const int jl   = i & 15;
    const int slot = (jl & 3) | ((jl & 4) << 1) | ((jl & 8) >> 1);  // swap b2<->b3

    #pragma unroll
    for (int ch = 0; ch < 2; ch++) {
        const int chunk = part * 2 + ch;

        float a[8];
        #pragma unroll
        for (int o = 0; o < 8; o++) a[o] = 0.f;
        #pragma unroll
        for (int c4 = 0; c4 < 4; c4++) {
            #pragma unroll
            for (int o = 0; o < 8; o++) {
                const float4 wv4 = ((const float4*)wlds)[(ch * 8 + o) * 16 + wv * 4 + c4];
                a[o] += wv4.x * xv[c4*4+0] + wv4.y * xv[c4*4+1]
                      + wv4.z * xv[c4*4+2] + wv4.w * xv[c4*4+3];
            }
        }
        if (ch) __syncthreads();         // pacc free from previous chunk
        #pragma unroll
        for (int o = 0; o < 8; o++) pacc[wv][lane][o] = a[o];
        __syncthreads();

        // epilogue: thread = (voxel = lane, outputs o in [2*wv, 2*wv+2))
        const int ob = 2 * wv;
        float fin[2];
        #pragma unroll
        for (int oo = 0; oo < 2; oo++)
            fin[oo] = ((pacc[0][lane][ob + oo] + pacc[1][lane][ob + oo])
                    +  (pacc[2][lane][ob + oo] + pacc[3][lane][ob + oo]))
                    + blds[ch * 8 + ob + oo];

        if (chunk < 2) {
            if (chunk == 0) {
                const float LOG2E = 1.4426950408889634f;
                fin[0] *= LOG2E; fin[1] *= LOG2E;
            }
            unsigned short hu[2], lu[2];
            #pragma unroll
            for (int oo = 0; oo < 2; oo++) {
                hu[oo] = f2bf(fin[oo]);
                lu[oo] = f2bf(fin[oo] - bf2f(hu[oo]));
            }
            unsigned short* dst = (chunk == 0 ? qt2 : kt2) + row * 16 + ob;
            *(unsigned*)dst       = *(const unsigned*)hu;
            *(unsigned*)(dst + 8) = *(const unsigned*)lu;
        } else {
            const int cbase = (chunk - 2) * 8 + ob;
            unsigned short* vdst =
                vt + ((size_t)b * 256 + (i >> 4)) * 1024 + (size_t)cbase * 16 + slot;
            vdst[0]  = f2bf(fin[0]);
            vdst[16] = f2bf(fin[1]);
        }
    }
}

// ---------------------------------------------------------------------------
// Kernel 2: fused flash attention with WAVE-PAIRING — BYTE-IDENTICAL to R17
// (the winner: pairs share K/V addresses -> trailing wave hits L1; lean
// 32q-per-wave registers; 16 waves/block, grid 256).
// ---------------------------------------------------------------------------
__global__ __launch_bounds__(1024)
void attn_kernel(const unsigned short* __restrict__ qt2,
                 const unsigned short* __restrict__ kt2,
                 const unsigned short* __restrict__ vt,
                 const float* __restrict__ x,
                 const float* __restrict__ gamma,
                 float* __restrict__ out)
{
    __shared__ float slds[4][64][64];   // merge slots [c][q 0..63], 64 KB
    __shared__ float sldl[4][64];       // l per slot

    const int t    = threadIdx.x;       // 0..1023
    const int l    = t & 63;
    const int wv   = t >> 6;            // 0..15
    const int qt   = wv & 1;            // q-tile of this wave (pairing key)
    const int u    = wv >> 1;           // 0..7 j-range id (shared by pair)
    const int lo31 = l & 31;
    const int h    = l >> 5;
    const int w     = blockIdx.x;
    const int b     = w >> 6;
    const int qbase = (w & 63) << 6;    // 64 q per block
    const int j0    = u << 9;           // 512 j per wave

    // Q B-frags: B1 = [q_hi|q_hi], B2 = [q_lo|0]
    const unsigned short* qrow =
        qt2 + ((size_t)b * NTOK + qbase + qt * 32 + lo31) * 16;
    s16x8 qB1 = *(const s16x8*)qrow;
    s16x8 qB2;
    if (h == 0) qB2 = *(const s16x8*)(qrow + 8);
    else        { u32x4 z = {0,0,0,0}; qB2 = __builtin_bit_cast(s16x8, z); }

    // K/V addresses depend only on (b, h, lo31, j0) -> identical for a pair
    const unsigned short* kb  = kt2 + (size_t)b * NTOK * 16 + (size_t)h * 8;
    const unsigned short* vbA = vt + (size_t)b * NTOK * 64 + (size_t)lo31 * 16 + 8 * h;
    const unsigned short* vbB = vbA + 512;

    f32x16 accA, accB;
    #pragma unroll
    for (int r = 0; r < 16; r++) { accA[r] = 0.f; accB[r] = 0.f; }
    float lsum = 0.f;

    s16x8 K[2], V00[2], V01[2], V10[2], V11[2];

    #define LOADSET(s_, a_) do {                                              \
        K[s_]   = *(const s16x8*)(kb + (size_t)(j0 + ((a_) << 5) + lo31) * 16);  \
        V00[s_] = *(const s16x8*)(vbA + (size_t)((j0 >> 4) + ((a_) << 1)) * 1024);     \
        V01[s_] = *(const s16x8*)(vbA + (size_t)((j0 >> 4) + ((a_) << 1) + 1) * 1024); \
        V10[s_] = *(const s16x8*)(vbB + (size_t)((j0 >> 4) + ((a_) << 1)) * 1024);     \
        V11[s_] = *(const s16x8*)(vbB + (size_t)((j0 >> 4) + ((a_) << 1) + 1) * 1024); \
    } while (0)

    LOADSET(0, 0);

    #pragma unroll
    for (int it = 0; it < 16; ++it) {
        const int cu = it & 1;
        const int nx = it + 1;
        LOADSET(cu ^ 1, (nx < 16) ? nx : 0);   // issue next-chunk loads first

        f32x16 s;
        #pragma unroll
        for (int r = 0; r < 16; r++) s[r] = 0.f;
        s = __builtin_amdgcn_mfma_f32_32x32x16_bf16(K[cu], qB1, s, 0, 0, 0);
        s = __builtin_amdgcn_mfma_f32_32x32x16_bf16(K[cu], qB2, s, 0, 0, 0);

        // ---- p = exp2(s) raw (no max needed: CQ=8 keeps |s| small) ----
        #pragma unroll
        for (int r = 0; r < 16; r++) s[r] = __builtin_amdgcn_exp2f(s[r]);

        lsum += ((s[0]+s[1])+(s[2]+s[3])) + ((s[4]+s[5])+(s[6]+s[7]))
              + ((s[8]+s[9])+(s[10]+s[11])) + ((s[12]+s[13])+(s[14]+s[15]));

        // ---- P^T -> B-frags: direct repack of own registers ----
        u32x4 wa, wc;
        wa.x = pk2(s[0], s[1]);   wa.y = pk2(s[2], s[3]);
        wa.z = pk2(s[4], s[5]);   wa.w = pk2(s[6], s[7]);
        wc.x = pk2(s[8], s[9]);   wc.y = pk2(s[10], s[11]);
        wc.z = pk2(s[12], s[13]); wc.w = pk2(s[14], s[15]);
        s16x8 pf0 = __builtin_bit_cast(s16x8, wa);
        s16x8 pf1 = __builtin_bit_cast(s16x8, wc);

        __builtin_amdgcn_s_setprio(1);
        accA = __builtin_amdgcn_mfma_f32_32x32x16_bf16(V00[cu], pf0, accA, 0, 0, 0);
        accA = __builtin_amdgcn_mfma_f32_32x32x16_bf16(V01[cu], pf1, accA, 0, 0, 0);
        accB = __builtin_amdgcn_mfma_f32_32x32x16_bf16(V10[cu], pf0, accB, 0, 0, 0);
        accB = __builtin_amdgcn_mfma_f32_32x32x16_bf16(V11[cu], pf1, accB, 0, 0, 0);
        __builtin_amdgcn_s_setprio(0);
    }

    // combine halves of l once
    lsum += __shfl_xor(lsum, 32);

    // ---- per-q-tile additive LDS tree merge (disjoint columns qt*32+..) ----
    #define WR_SLOT(sidx) do {                                                \
        const int s_ = (sidx);                                                \
        _Pragma("unroll")                                                     \
        for (int r = 0; r < 16; r++) {                                        \
            const int c_ = (r & 3) + 8 * (r >> 2) + 4 * h;                    \
            slds[s_][c_][qt * 32 + lo31]      = accA[r];                      \
            slds[s_][c_ + 32][qt * 32 + lo31] = accB[r];                      \
        }                                                                     \
        if (h == 0) sldl[s_][qt * 32 + lo31] = lsum;                          \
    } while (0)

    #define MRG_SLOT(sidx) do {                                               \
        const int s_ = (sidx);                                                \
        _Pragma("unroll")                                                     \
        for (int r = 0; r < 16; r++) {                                        \
            const int c_ = (r & 3) + 8 * (r >> 2) + 4 * h;                    \
            accA[r] += slds[s_][c_][qt * 32 + lo31];                          \
            accB[r] += slds[s_][c_ + 32][qt * 32 + lo31];                     \
        }                                                                     \
        lsum += sldl[s_][qt * 32 + lo31];                                     \
    } while (0)

    if (u >= 4) WR_SLOT(u - 4);
    __syncthreads();
    if (u < 4) MRG_SLOT(u);
    __syncthreads();
    if (u == 2 || u == 3) WR_SLOT(u - 2);
    __syncthreads();
    if (u < 2) MRG_SLOT(u);
    __syncthreads();
    if (u == 1) WR_SLOT(0);
    __syncthreads();
    if (u == 0) { MRG_SLOT(0); WR_SLOT(0); }
    __syncthreads();

    // ---- fused epilogue: out = gamma*acc/L + x, all 1024 threads ----
    const int c  = t >> 4;              // 0..63
    const int q4 = (t & 15) << 2;       // 0,4,..,60
    const float g = gamma[0];
    const float4 a4 = *(const float4*)&slds[0][c][q4];
    const float g0 = g / sldl[0][q4 + 0];
    const float g1 = g / sldl[0][q4 + 1];
    const float g2 = g / sldl[0][q4 + 2];
    const float g3 = g / sldl[0][q4 + 3];
    const size_t off = (((size_t)b * 64 + c) << 12) + qbase + q4;
    const float4 xv4 = *(const float4*)(x + off);
    float4 o;
    o.x = a4.x * g0 + xv4.x;
    o.y = a4.y * g1 + xv4.y;
    o.z = a4.z * g2 + xv4.z;
    o.w = a4.w * g3 + xv4.w;
    *(float4*)(out + off) = o;
}

// ---------------------------------------------------------------------------
extern "C" void kernel_launch(void* const* d_in, const int* in_sizes, int n_in,
                              void* d_out, int out_size, void* d_ws, size_t ws_size,
                              hipStream_t stream) {
    const float* x     = (const float*)d_in[0];
    const float* Wq    = (const float*)d_in[1];
    const float* bq    = (const float*)d_in[2];
    const float* Wk    = (const float*)d_in[3];
    const float* bk    = (const float*)d_in[4];
    const float* Wv    = (const float*)d_in[5];
    const float* bv    = (const float*)d_in[6];
    const float* gamma = (const float*)d_in[7];
    float* out = (float*)d_out;

    unsigned short* qt2 = (unsigned short*)d_ws;            // 4*4096*16 bf16
    unsigned short* kt2 = qt2 + (size_t)4 * NTOK * 16;      // 4*4096*16 bf16
    unsigned short* vt  = kt2 + (size_t)4 * NTOK * 16;      // 4*4096*64 bf16 (tiled+permuted)

    qkv_kernel<<<1280, 256, 0, stream>>>(x, Wq, bq, Wk, bk, Wv, bv, qt2, kt2, vt);
    attn_kernel<<<256, 1024, 0, stream>>>(qt2, kt2, vt, x, gamma, out);
}